// Round 2
// baseline (368.039 us; speedup 1.0000x reference)
//
#include <hip/hip_runtime.h>

// result = sum_i | sum_j flow[i,j] - sum_j flow[j,i] |, N=8192 fp32.
// One streaming pass builds diff[i] = row_sum[i] - col_sum[i] (atomics into
// d_ws), then a tiny kernel reduces sum(|diff|) into d_out[0].
//
// R2 restructure: each wave sweeps ALONG a row (8 independent float4 loads,
// register row-partial), ONE 64-lane shuffle reduce per row (was: one per
// load). Column sums are pure register accumulators (8 x float4 / thread),
// cross-wave reduced in LDS once per block. VMEM:DS ratio 8:0.75 vs 1:6.

constexpr int N = 8192;
constexpr int N4 = N / 4;          // 2048 float4 per row
constexpr int CQ4 = N4 / 4;        // 512 float4 per column-quarter

__global__ __launch_bounds__(256) void tile_sums_kernel(
    const float* __restrict__ flow, float* __restrict__ diff) {
  const int wave = threadIdx.x >> 6;
  const int lane = threadIdx.x & 63;
  const int c4base = blockIdx.x * CQ4;         // this block's column quarter
  const int row0 = blockIdx.y * 64 + wave * 16;  // 16 consecutive rows / wave

  const float4* __restrict__ flow4 = reinterpret_cast<const float4*>(flow);

  float4 colacc[8];
#pragma unroll
  for (int j = 0; j < 8; ++j) colacc[j] = make_float4(0.f, 0.f, 0.f, 0.f);

  for (int i = 0; i < 16; ++i) {
    const int r = row0 + i;
    const float4* __restrict__ rowp = flow4 + (size_t)r * N4 + c4base + lane;
    float4 v[8];
#pragma unroll
    for (int j = 0; j < 8; ++j) v[j] = rowp[j * 64];  // 8 independent 1KB/wave loads

    float rs = 0.f;
#pragma unroll
    for (int j = 0; j < 8; ++j) {
      colacc[j].x += v[j].x; colacc[j].y += v[j].y;
      colacc[j].z += v[j].z; colacc[j].w += v[j].w;
      rs += (v[j].x + v[j].y) + (v[j].z + v[j].w);
    }
    // one 64-lane reduction per ROW (not per load)
#pragma unroll
    for (int off = 32; off > 0; off >>= 1) rs += __shfl_down(rs, off, 64);
    if (lane == 0) atomicAdd(&diff[r], rs);
  }

  // cross-wave column reduce: LDS [4 waves][512 float4] = 32 KB
  __shared__ float4 lds[4][CQ4];
#pragma unroll
  for (int j = 0; j < 8; ++j) lds[wave][j * 64 + lane] = colacc[j];
  __syncthreads();
#pragma unroll
  for (int p = threadIdx.x; p < CQ4; p += 256) {
    float4 a = lds[0][p], b = lds[1][p], c = lds[2][p], d = lds[3][p];
    const int col = (c4base + p) * 4;
    atomicAdd(&diff[col + 0], -((a.x + b.x) + (c.x + d.x)));
    atomicAdd(&diff[col + 1], -((a.y + b.y) + (c.y + d.y)));
    atomicAdd(&diff[col + 2], -((a.z + b.z) + (c.z + d.z)));
    atomicAdd(&diff[col + 3], -((a.w + b.w) + (c.w + d.w)));
  }
}

__global__ __launch_bounds__(1024) void abs_reduce_kernel(
    const float* __restrict__ diff, float* __restrict__ out) {
  const float4* __restrict__ d4 = reinterpret_cast<const float4*>(diff);
  float s = 0.f;
#pragma unroll
  for (int i = threadIdx.x; i < N4; i += 1024) {
    float4 v = d4[i];
    s += (fabsf(v.x) + fabsf(v.y)) + (fabsf(v.z) + fabsf(v.w));
  }
#pragma unroll
  for (int off = 32; off > 0; off >>= 1) s += __shfl_down(s, off, 64);

  __shared__ float wsum[16];
  if ((threadIdx.x & 63) == 0) wsum[threadIdx.x >> 6] = s;
  __syncthreads();
  if (threadIdx.x < 64) {
    float t = (threadIdx.x < 16) ? wsum[threadIdx.x] : 0.f;
#pragma unroll
    for (int off = 8; off > 0; off >>= 1) t += __shfl_down(t, off, 64);
    if (threadIdx.x == 0) out[0] = t;
  }
}

extern "C" void kernel_launch(void* const* d_in, const int* in_sizes, int n_in,
                              void* d_out, int out_size, void* d_ws, size_t ws_size,
                              hipStream_t stream) {
  const float* flow = (const float*)d_in[0];
  float* out = (float*)d_out;
  float* diff = (float*)d_ws;  // N floats = 32 KB

  hipMemsetAsync(diff, 0, (size_t)N * sizeof(float), stream);

  dim3 grid(4, N / 64);  // 4 column quarters x 128 row strips = 512 blocks
  tile_sums_kernel<<<grid, 256, 0, stream>>>(flow, diff);
  abs_reduce_kernel<<<1, 1024, 0, stream>>>(diff, out);
}